// Round 10
// baseline (96.183 us; speedup 1.0000x reference)
//
#include <hip/hip_runtime.h>
#include <hip/hip_bf16.h>

// ---------------------------------------------------------------------------
// AlsoDecoder, folded + fp16 MFMA end-to-end, dual-stream edge loop:
//   S[p] = feats[p]@W_f - pcd[p]@W_p + b_in   (MFMA prep kernel, fp16 table)
//   x1 = S[col] + also_pts[row]@W_p           (Q rebuilt per edge, L2-resident)
//   y  = relu(x1) @ W1                        (mfma 16x16x32 f16, swapped)
//   h2 = relu(y + b1)                         (packed-f16 fold epilogue)
//   logits = h2 @ (W2@W_out) + (b2@W_out+b_out)      (layer 3 folded)
//   probs = softmax(logits) == sigmoid(logit diff)
// Each wave processes TWO 16-edge groups per iteration (independent A/B
// register streams) to double outstanding gather misses, with 1-ahead gather
// and 2-ahead index prefetch.
// ---------------------------------------------------------------------------

typedef _Float16 half8 __attribute__((ext_vector_type(8)));
typedef _Float16 half2v __attribute__((ext_vector_type(2)));
typedef __fp16   fp16x2 __attribute__((ext_vector_type(2)));
typedef __attribute__((ext_vector_type(4))) float f32x4;

union U84h { uint4 u; half8 h; };
union UPH  { half2v h; fp16x2 f; int i; unsigned u; };

__device__ __forceinline__ half2v cvt2h(float a, float b) {
    UPH t;
    t.f = __builtin_amdgcn_cvt_pkrtz(a, b);
    return t.h;
}

__device__ __forceinline__ half8 relu8(half8 v) {
    half8 z;
#pragma unroll
    for (int i = 0; i < 8; ++i) z[i] = (_Float16)0.f;
    return __builtin_elementwise_max(v, z);
}

// ---------------- prep: pack weights --------------------------------------
__global__ __launch_bounds__(256) void pack_fold(
    const float* __restrict__ w1, const float* __restrict__ w_in,
    const float* __restrict__ b1, const float* __restrict__ w2,
    const float* __restrict__ w_out, const float* __restrict__ b2,
    const float* __restrict__ b_out,
    _Float16* __restrict__ w1f, _Float16* __restrict__ wAf,
    _Float16* __restrict__ wpf, _Float16* __restrict__ w0h,
    _Float16* __restrict__ w1h, _Float16* __restrict__ b1h,
    float* __restrict__ bf) {
    int t = blockIdx.x * 256 + threadIdx.x;
    if (t < 4096) {
        int f = t >> 9, lane = (t >> 3) & 63, j = t & 7;
        int ntile = f >> 1, kstep = f & 1;
        int k = kstep * 32 + ((lane >> 4) << 3) + j;
        int n = ntile * 16 + (lane & 15);
        w1f[t] = (_Float16)w1[k * 64 + n];
    } else if (t < 10240) {
        int i = t - 4096;
        int f = i >> 9, lane = (i >> 3) & 63, j = i & 7;
        int ntile = f / 3, ks = f % 3;
        int n = ntile * 16 + (lane & 15);
        float v;
        if (ks < 2) {
            int k = ks * 32 + ((lane >> 4) << 3) + j;
            v = w_in[k * 64 + n];
        } else {
            v = ((lane >> 4) == 0 && j < 3) ? -w_in[(64 + j) * 64 + n] : 0.f;
        }
        wAf[i] = (_Float16)v;
    } else if (t < 13312) {
        int i = t - 10240;                      // d*1024 + ks*512 + lane*8 + j
        int d = i >> 10, ks = (i >> 9) & 1, lane = (i >> 3) & 63, j = i & 7;
        int k = ks * 32 + ((lane >> 4) << 3) + j;
        wpf[i] = (_Float16)w_in[(64 + d) * 64 + k];
    } else if (t < 13376) {
        int n = t - 13312;
        float s0 = 0.f, s1 = 0.f;
#pragma unroll
        for (int j = 0; j < 64; ++j) {
            s0 = fmaf(w2[n * 64 + j], w_out[j * 2 + 0], s0);
            s1 = fmaf(w2[n * 64 + j], w_out[j * 2 + 1], s1);
        }
        w0h[n] = (_Float16)s0;
        w1h[n] = (_Float16)s1;
    } else if (t < 13440) {
        int n = t - 13376;
        b1h[n] = (_Float16)b1[n];
    } else if (t == 13440) {
        float s0 = b_out[0], s1 = b_out[1];
#pragma unroll
        for (int j = 0; j < 64; ++j) {
            s0 = fmaf(b2[j], w_out[j * 2 + 0], s0);
            s1 = fmaf(b2[j], w_out[j * 2 + 1], s1);
        }
        bf[0] = s0; bf[1] = s1;
    }
}

// ---------------- prep: S table via MFMA -----------------------------------
__global__ __launch_bounds__(256) void precompute_S(
    const float* __restrict__ feats, const float* __restrict__ pcd,
    const float* __restrict__ b_in, const half8* __restrict__ wAf,
    _Float16* __restrict__ S, int N) {
    int lane = threadIdx.x & 63;
    int idx = lane & 15, g = lane >> 4;
    int base = (blockIdx.x * 4 + (threadIdx.x >> 6)) * 16;
    if (base >= N) return;

    half8 wa[12];
#pragma unroll
    for (int f = 0; f < 12; ++f) wa[f] = wAf[f * 64 + lane];

    int p = base + idx;
    int ps = p < N ? p : N - 1;
    const float4* fp = (const float4*)(feats + (size_t)ps * 64);
    float4 f0 = fp[2 * g], f1 = fp[2 * g + 1];
    float4 f2 = fp[8 + 2 * g], f3 = fp[8 + 2 * g + 1];
    half8 b0, b1v, b2v;
    b0[0]=(_Float16)f0.x; b0[1]=(_Float16)f0.y; b0[2]=(_Float16)f0.z; b0[3]=(_Float16)f0.w;
    b0[4]=(_Float16)f1.x; b0[5]=(_Float16)f1.y; b0[6]=(_Float16)f1.z; b0[7]=(_Float16)f1.w;
    b1v[0]=(_Float16)f2.x; b1v[1]=(_Float16)f2.y; b1v[2]=(_Float16)f2.z; b1v[3]=(_Float16)f2.w;
    b1v[4]=(_Float16)f3.x; b1v[5]=(_Float16)f3.y; b1v[6]=(_Float16)f3.z; b1v[7]=(_Float16)f3.w;
    float px = 0.f, py = 0.f, pz = 0.f;
    if (g == 0) {
        const float* pp = pcd + (size_t)ps * 3;
        px = pp[0]; py = pp[1]; pz = pp[2];
    }
#pragma unroll
    for (int i = 0; i < 8; ++i) b2v[i] = (_Float16)0.f;
    b2v[0] = (_Float16)px; b2v[1] = (_Float16)py; b2v[2] = (_Float16)pz;

#pragma unroll
    for (int tt = 0; tt < 4; ++tt) {
        f32x4 bi = *(const f32x4*)(b_in + tt * 16 + 4 * g);
        f32x4 acc;
        acc = __builtin_amdgcn_mfma_f32_16x16x32_f16(wa[tt * 3 + 0], b0, bi, 0, 0, 0);
        acc = __builtin_amdgcn_mfma_f32_16x16x32_f16(wa[tt * 3 + 1], b1v, acc, 0, 0, 0);
        acc = __builtin_amdgcn_mfma_f32_16x16x32_f16(wa[tt * 3 + 2], b2v, acc, 0, 0, 0);
        union { uint2 u; _Float16 h[4]; } o;
        o.h[0] = (_Float16)acc[0]; o.h[1] = (_Float16)acc[1];
        o.h[2] = (_Float16)acc[2]; o.h[3] = (_Float16)acc[3];
        if (p < N) *(uint2*)(S + (size_t)p * 64 + tt * 16 + 4 * g) = o.u;
    }
}

// ---------------- edge kernel --------------------------------------------
__global__ __launch_bounds__(256) void edge_mfma(
    const _Float16* __restrict__ S, const float* __restrict__ also_pts,
    const int* __restrict__ row, const int* __restrict__ col,
    const int* __restrict__ labels,
    const half8* __restrict__ w1f, const half8* __restrict__ wpf,
    const unsigned* __restrict__ w0p, const unsigned* __restrict__ w1p,
    const unsigned* __restrict__ b1p, const float* __restrict__ bfold,
    float* __restrict__ out, int E, int npairs) {
    __shared__ half8 wf_lds[8][64];
    {
        int t = threadIdx.x;
        wf_lds[t >> 6][t & 63] = w1f[t];
        wf_lds[(t + 256) >> 6][t & 63] = w1f[t + 256];
    }
    __syncthreads();

    int lane = threadIdx.x & 63;
    int idx  = lane & 15;          // edge-in-group (D col)
    int g    = lane >> 4;
    int wid  = blockIdx.x * 4 + (threadIdx.x >> 6);
    int nw   = gridDim.x * 4;
    if (wid >= npairs) return;

    // persistent per-lane constants
    half8 wpd[3][2];
#pragma unroll
    for (int d = 0; d < 3; ++d)
#pragma unroll
        for (int ks = 0; ks < 2; ++ks) wpd[d][ks] = wpf[(d * 2 + ks) * 64 + lane];
    UPH w0v[8], w1v[8], b1v[8];
#pragma unroll
    for (int tt = 0; tt < 4; ++tt)
#pragma unroll
        for (int h = 0; h < 2; ++h) {
            int i = tt * 8 + 2 * g + h;
            w0v[tt * 2 + h].u = w0p[i];
            w1v[tt * 2 + h].u = w1p[i];
            b1v[tt * 2 + h].u = b1p[i];
        }
    float bfd = bfold[0] - bfold[1];   // bf0 - bf1 (only diff matters)
    half2v zero2 = {(_Float16)0.f, (_Float16)0.f};

    auto ldidx = [&](int p, int s, int& r, int& c) {
        int e = (2 * p + s) * 16 + idx;
        e = e < E ? e : E - 1;
        r = row[e]; c = col[e];
    };
    auto gath = [&](int r, int c, uint4& s0, uint4& s1,
                    float& ax, float& ay, float& az, int& lb) {
        const uint4* sp = (const uint4*)(S + (size_t)c * 64);
        s0 = sp[g]; s1 = sp[4 + g];
        const float* ap = also_pts + (size_t)r * 3;
        ax = ap[0]; ay = ap[1]; az = ap[2];
        lb = labels[r];
    };
    auto comp = [&](int gg, uint4 s0r, uint4 s1r,
                    float ax, float ay, float az, int lb) {
        int e = gg * 16 + idx;
        bool eok = e < E;
        U84h s0u, s1u; s0u.u = s0r; s1u.u = s1r;
        _Float16 ah = (_Float16)ax, bh = (_Float16)ay, ch = (_Float16)az;
        half8 av = {ah, ah, ah, ah, ah, ah, ah, ah};
        half8 bv = {bh, bh, bh, bh, bh, bh, bh, bh};
        half8 cv = {ch, ch, ch, ch, ch, ch, ch, ch};
        half8 q0 = av * wpd[0][0] + bv * wpd[1][0] + cv * wpd[2][0];
        half8 q1 = av * wpd[0][1] + bv * wpd[1][1] + cv * wpd[2][1];
        half8 x0 = relu8(s0u.h + q0);
        half8 x1 = relu8(s1u.h + q1);

        f32x4 zero = {0.f, 0.f, 0.f, 0.f};
        f32x4 acc[4];
#pragma unroll
        for (int tt = 0; tt < 4; ++tt) {
            acc[tt] = __builtin_amdgcn_mfma_f32_16x16x32_f16(wf_lds[2 * tt][lane],     x0, zero, 0, 0, 0);
            acc[tt] = __builtin_amdgcn_mfma_f32_16x16x32_f16(wf_lds[2 * tt + 1][lane], x1, acc[tt], 0, 0, 0);
        }

        half2v p0 = zero2, p1 = zero2;
#pragma unroll
        for (int tt = 0; tt < 4; ++tt) {
            half2v h01 = cvt2h(acc[tt][0], acc[tt][1]);
            half2v h23 = cvt2h(acc[tt][2], acc[tt][3]);
            h01 = __builtin_elementwise_max(h01 + b1v[tt * 2 + 0].h, zero2);
            h23 = __builtin_elementwise_max(h23 + b1v[tt * 2 + 1].h, zero2);
            p0 += h01 * w0v[tt * 2 + 0].h + h23 * w0v[tt * 2 + 1].h;
            p1 += h01 * w1v[tt * 2 + 0].h + h23 * w1v[tt * 2 + 1].h;
        }
        UPH P0, P1, T;
        P0.h = p0; P1.h = p1;
        T.i = __shfl_xor(P0.i, 16); P0.h += T.h;
        T.i = __shfl_xor(P0.i, 32); P0.h += T.h;
        T.i = __shfl_xor(P1.i, 16); P1.h += T.h;
        T.i = __shfl_xor(P1.i, 32); P1.h += T.h;

        if (g == 0 && eok) {
            float l0 = (float)P0.h[0] + (float)P0.h[1];
            float l1 = (float)P1.h[0] + (float)P1.h[1];
            // softmax over 2 classes == sigmoid of logit difference
            float u = __expf(l1 - l0 - bfd);
            float pa = 1.f / (1.f + u);
            *(float2*)(out + (size_t)e * 2) = make_float2(pa, 1.f - pa);
            out[(size_t)2 * E + e] = (float)lb;
        }
    };

    // ---- dual-stream pipeline: gathers 1-ahead, indices 2-ahead ----
    int pair = wid, stride = nw;
    int rA, cA, rB, cB;
    ldidx(pair, 0, rA, cA);
    ldidx(pair, 1, rB, cB);
    uint4 s0A, s1A, s0B, s1B;
    float axA, ayA, azA, axB, ayB, azB;
    int lbA, lbB;
    gath(rA, cA, s0A, s1A, axA, ayA, azA, lbA);
    gath(rB, cB, s0B, s1B, axB, ayB, azB, lbB);
    int pn = pair + stride; pn = pn < npairs ? pn : pair;
    int rAn, cAn, rBn, cBn;
    ldidx(pn, 0, rAn, cAn);
    ldidx(pn, 1, rBn, cBn);

    for (; pair < npairs; pair += stride) {
        // issue gathers for i+1
        uint4 t0A, t1A, t0B, t1B;
        float nxA, nyA, nzA, nxB, nyB, nzB;
        int nlA, nlB;
        gath(rAn, cAn, t0A, t1A, nxA, nyA, nzA, nlA);
        gath(rBn, cBn, t0B, t1B, nxB, nyB, nzB, nlB);
        // indices for i+2
        int p2 = pair + 2 * stride; p2 = p2 < npairs ? p2 : pair;
        int rA2, cA2, rB2, cB2;
        ldidx(p2, 0, rA2, cA2);
        ldidx(p2, 1, rB2, cB2);

        // compute both current streams
        comp(2 * pair,     s0A, s1A, axA, ayA, azA, lbA);
        comp(2 * pair + 1, s0B, s1B, axB, ayB, azB, lbB);

        // rotate
        s0A = t0A; s1A = t1A; axA = nxA; ayA = nyA; azA = nzA; lbA = nlA;
        s0B = t0B; s1B = t1B; axB = nxB; ayB = nyB; azB = nzB; lbB = nlB;
        rAn = rA2; cAn = cA2; rBn = rB2; cBn = cB2;
    }
}

extern "C" void kernel_launch(void* const* d_in, const int* in_sizes, int n_in,
                              void* d_out, int out_size, void* d_ws, size_t ws_size,
                              hipStream_t stream) {
    const float* pcd      = (const float*)d_in[0];
    const float* feats    = (const float*)d_in[1];
    const float* also_pts = (const float*)d_in[2];
    const int*   labels   = (const int*)d_in[3];
    const int*   row      = (const int*)d_in[4];
    const int*   col      = (const int*)d_in[5];
    const float* w_in     = (const float*)d_in[6];
    const float* b_in     = (const float*)d_in[7];
    const float* w1       = (const float*)d_in[8];
    const float* b1       = (const float*)d_in[9];
    const float* w2       = (const float*)d_in[10];
    const float* b2       = (const float*)d_in[11];
    const float* w_out    = (const float*)d_in[12];
    const float* b_out    = (const float*)d_in[13];

    int N = in_sizes[0] / 3;
    int E = in_sizes[4];

    _Float16* Sb  = (_Float16*)d_ws;
    _Float16* w1f = Sb + (size_t)N * 64;
    _Float16* wAf = w1f + 4096;
    _Float16* wpf = wAf + 6144;
    _Float16* w0h = wpf + 3072;
    _Float16* w1h = w0h + 64;
    _Float16* b1h = w1h + 64;
    float*    bf  = (float*)(b1h + 64);

    pack_fold<<<53, 256, 0, stream>>>(w1, w_in, b1, w2, w_out, b2, b_out,
                                      w1f, wAf, wpf, w0h, w1h, b1h, bf);

    int ngroupsS = (N + 15) / 16;
    precompute_S<<<(ngroupsS + 3) / 4, 256, 0, stream>>>(
        feats, pcd, b_in, (const half8*)wAf, Sb, N);

    int ngroups = (E + 15) / 16;
    int npairs  = (ngroups + 1) / 2;
    edge_mfma<<<3072, 256, 0, stream>>>(Sb, also_pts, row, col, labels,
                                        (const half8*)w1f, (const half8*)wpf,
                                        (const unsigned*)w0h, (const unsigned*)w1h,
                                        (const unsigned*)b1h, bf,
                                        (float*)d_out, E, npairs);
}